// Round 1
// baseline (154.655 us; speedup 1.0000x reference)
//
#include <hip/hip_runtime.h>

// Problem constants (B=2, S=512, D=128, DG=64, NG=2)
#define BQ 2
#define SQ 512
#define DQ 128
#define DGQ 64
#define NGQ 2

// ---------------------------------------------------------------------------
// Kernel A: per-row projections.
//   Q = x@Wq, K = x@Wk, V = x@Wv   (rows of length 128)
//   QW1[row, g*64+c] = sum_e Q[row, g*64+e] * W1[e,c] + b1[c]
//   KW1[row, g*64+c] = sum_e K[row, g*64+e] * W1[e,c]
// Exploits linearity: relu((Q_i - K_j)@W1 + b1) == relu(QW1_i - KW1_j).
// 4 rows per block so each Wq/Wk/Wv column load feeds 4 FMAs.
// ---------------------------------------------------------------------------
__global__ __launch_bounds__(128) void proj_kernel(
    const float* __restrict__ x,
    const float* __restrict__ Wq, const float* __restrict__ Wk,
    const float* __restrict__ Wv,
    const float* __restrict__ W1, const float* __restrict__ b1,
    float* __restrict__ QW1, float* __restrict__ KW1, float* __restrict__ Vw)
{
    const int t = threadIdx.x;          // 0..127 = output feature
    const int row0 = blockIdx.x * 4;    // flat (b*S + s)

    __shared__ float xs[4][DQ];
    __shared__ float qs[4][DQ];
    __shared__ float ks[4][DQ];

    #pragma unroll
    for (int r = 0; r < 4; ++r)
        xs[r][t] = x[(size_t)(row0 + r) * DQ + t];
    __syncthreads();

    float aq[4] = {0.f, 0.f, 0.f, 0.f};
    float ak[4] = {0.f, 0.f, 0.f, 0.f};
    float av[4] = {0.f, 0.f, 0.f, 0.f};
    #pragma unroll 4
    for (int e = 0; e < DQ; ++e) {
        const float wq = Wq[e * DQ + t];
        const float wk = Wk[e * DQ + t];
        const float wv = Wv[e * DQ + t];
        #pragma unroll
        for (int r = 0; r < 4; ++r) {
            aq[r] = fmaf(xs[r][e], wq, aq[r]);
            ak[r] = fmaf(xs[r][e], wk, ak[r]);
            av[r] = fmaf(xs[r][e], wv, av[r]);
        }
    }
    #pragma unroll
    for (int r = 0; r < 4; ++r) {
        qs[r][t] = aq[r];
        ks[r][t] = ak[r];
        Vw[(size_t)(row0 + r) * DQ + t] = av[r];
    }
    __syncthreads();

    const int g = t >> 6, c = t & 63;   // group, output channel of W1
    float q1[4], k1[4];
    #pragma unroll
    for (int r = 0; r < 4; ++r) { q1[r] = b1[c]; k1[r] = 0.f; }
    #pragma unroll 4
    for (int e = 0; e < DGQ; ++e) {
        const float w = W1[e * DGQ + c];
        #pragma unroll
        for (int r = 0; r < 4; ++r) {
            q1[r] = fmaf(qs[r][g * DGQ + e], w, q1[r]);
            k1[r] = fmaf(ks[r][g * DGQ + e], w, k1[r]);
        }
    }
    #pragma unroll
    for (int r = 0; r < 4; ++r) {
        QW1[(size_t)(row0 + r) * DQ + t] = q1[r];  // layout [B*S][NG*DG]
        KW1[(size_t)(row0 + r) * DQ + t] = k1[r];
    }
}

// ---------------------------------------------------------------------------
// Kernel B: one block per (b, g, i) softmax row.
//   For each key j: h1 = relu(QW1_i - KW1_j)      (64)
//                   h2 = relu(h1 @ W2 + b2)       (64x16 FMA - the hot loop)
//                   a  = relu(h2 @ W3 + b3)
//                   logit = a * pos_mul + pos_add
//   softmax over j, then out[b,i, dg*NG+g] = sum_j p_j * V[b,j, dg*NG+g].
// W2/W3/qrow indices are wave-uniform -> scalar loads; VALU is ~pure FMA.
// ---------------------------------------------------------------------------
__global__ __launch_bounds__(128) void attn_kernel(
    const float* __restrict__ QW1, const float* __restrict__ KW1,
    const float* __restrict__ Vw,
    const float* __restrict__ W2, const float* __restrict__ b2,
    const float* __restrict__ W3, const float* __restrict__ b3,
    const float* __restrict__ pos_add, const float* __restrict__ pos_mul,
    float* __restrict__ out)
{
    const int t = threadIdx.x;                 // 0..127
    const int i = blockIdx.x & (SQ - 1);       // query index
    const int g = (blockIdx.x >> 9) & (NGQ - 1);
    const int b = blockIdx.x >> 10;

    __shared__ float scores[SQ];
    __shared__ float red[4];
    __shared__ float avred[DGQ];

    const float* qrow = QW1 + ((size_t)(b * SQ + i)) * DQ + g * DGQ;
    const float* pa = pos_add + (size_t)g * SQ * SQ + (size_t)i * SQ;
    const float* pm = pos_mul + (size_t)g * SQ * SQ + (size_t)i * SQ;

    float w3r[16];
    #pragma unroll
    for (int o = 0; o < 16; ++o) w3r[o] = W3[o];
    const float b3r = b3[0];

    // ---- score passes: each thread does j = p*128 + t ----
    for (int p = 0; p < 4; ++p) {
        const int j = p * 128 + t;
        const float4* krow = reinterpret_cast<const float4*>(
            KW1 + ((size_t)(b * SQ + j)) * DQ + g * DGQ);
        float acc[16];
        #pragma unroll
        for (int o = 0; o < 16; ++o) acc[o] = b2[o];

        #pragma unroll 4
        for (int c4 = 0; c4 < 16; ++c4) {
            const float4 kv = krow[c4];
            const float h0 = fmaxf(qrow[c4 * 4 + 0] - kv.x, 0.f);
            const float h1 = fmaxf(qrow[c4 * 4 + 1] - kv.y, 0.f);
            const float h2 = fmaxf(qrow[c4 * 4 + 2] - kv.z, 0.f);
            const float h3 = fmaxf(qrow[c4 * 4 + 3] - kv.w, 0.f);
            const float* w2r = W2 + c4 * 64;   // W2[c][o], o fastest
            #pragma unroll
            for (int o = 0; o < 16; ++o) {
                acc[o] = fmaf(h0, w2r[o],      acc[o]);
                acc[o] = fmaf(h1, w2r[16 + o], acc[o]);
                acc[o] = fmaf(h2, w2r[32 + o], acc[o]);
                acc[o] = fmaf(h3, w2r[48 + o], acc[o]);
            }
        }
        float a = b3r;
        #pragma unroll
        for (int o = 0; o < 16; ++o) a = fmaf(fmaxf(acc[o], 0.f), w3r[o], a);
        a = fmaxf(a, 0.f);
        scores[j] = fmaf(a, pm[j], pa[j]);
    }
    __syncthreads();

    // ---- softmax over scores[0..511] ----
    float m = -3.4e38f;
    #pragma unroll
    for (int p = 0; p < 4; ++p) m = fmaxf(m, scores[p * 128 + t]);
    #pragma unroll
    for (int off = 32; off > 0; off >>= 1) m = fmaxf(m, __shfl_xor(m, off));
    const int wave = t >> 6;
    if ((t & 63) == 0) red[wave] = m;
    __syncthreads();
    m = fmaxf(red[0], red[1]);

    float s = 0.f;
    #pragma unroll
    for (int p = 0; p < 4; ++p) {
        const int j = p * 128 + t;
        const float e = __expf(scores[j] - m);
        scores[j] = e;   // own slots only: no race
        s += e;
    }
    #pragma unroll
    for (int off = 32; off > 0; off >>= 1) s += __shfl_xor(s, off);
    if ((t & 63) == 0) red[2 + wave] = s;
    __syncthreads();
    const float inv = 1.f / (red[2] + red[3]);

    // ---- A @ V (normalization folded into epilogue) ----
    const int dim = t & 63;      // dg index
    const int half = t >> 6;     // split key range across the 2 waves
    const float* vcol = Vw + ((size_t)(b * SQ + half * 256)) * DQ + dim * NGQ + g;
    float acc2 = 0.f;
    #pragma unroll 4
    for (int k = 0; k < 256; ++k)
        acc2 = fmaf(scores[half * 256 + k], vcol[(size_t)k * DQ], acc2);
    if (half == 1) avred[dim] = acc2;
    __syncthreads();
    if (half == 0) {
        out[((size_t)(b * SQ + i)) * DQ + dim * NGQ + g] =
            (acc2 + avred[dim]) * inv;
    }
}

extern "C" void kernel_launch(void* const* d_in, const int* in_sizes, int n_in,
                              void* d_out, int out_size, void* d_ws, size_t ws_size,
                              hipStream_t stream) {
    const float* x       = (const float*)d_in[0];
    const float* pos_add = (const float*)d_in[1];
    const float* pos_mul = (const float*)d_in[2];
    const float* Wq      = (const float*)d_in[3];
    const float* Wk      = (const float*)d_in[4];
    const float* Wv      = (const float*)d_in[5];
    const float* W1      = (const float*)d_in[6];
    const float* b1      = (const float*)d_in[7];
    const float* W2      = (const float*)d_in[8];
    const float* b2      = (const float*)d_in[9];
    const float* W3      = (const float*)d_in[10];
    const float* b3      = (const float*)d_in[11];
    float* out = (float*)d_out;

    float* ws  = (float*)d_ws;
    float* QW1 = ws;                    // [B*S][128] = 131072 floats
    float* KW1 = ws + 131072;           // [B*S][128]
    float* Vw  = ws + 262144;           // [B*S][128]

    proj_kernel<<<(BQ * SQ) / 4, 128, 0, stream>>>(x, Wq, Wk, Wv, W1, b1,
                                                   QW1, KW1, Vw);
    attn_kernel<<<BQ * NGQ * SQ, 128, 0, stream>>>(QW1, KW1, Vw, W2, b2, W3, b3,
                                                   pos_add, pos_mul, out);
}

// Round 2
// 137.816 us; speedup vs baseline: 1.1222x; 1.1222x over previous
//
#include <hip/hip_runtime.h>

// Problem constants (B=2, S=512, D=128, DG=64, NG=2)
#define BQ 2
#define SQ 512
#define DQ 128
#define DGQ 64
#define NGQ 2

// ws layout (floats):
//   Wq1 : [128][128] fused Wq @ blkdiag(W1,W1)      @ 0
//   Wk1 : [128][128] fused Wk @ blkdiag(W1,W1)      @ 16384
//   QW1 : [B*S][128]                                 @ 32768
//   KW1 : [B*S][128]                                 @ 163840
//   Vp  : [B*S][NG][DG] group-permuted V             @ 294912
// total 425984 floats = 1.66 MB

// ---------------------------------------------------------------------------
// Kernel 0: fuse W1 into the projection weights.
//   Wq1[d][g*64+c] = sum_e Wq[d][g*64+e] * W1[e][c]   (same for Wk1)
// 32768 outputs, 128 blocks x 256 threads, dot-length 64.
// W read is wave-uniform (scalar); W1 read is coalesced.
// ---------------------------------------------------------------------------
__global__ __launch_bounds__(256) void fuse_w_kernel(
    const float* __restrict__ Wq, const float* __restrict__ Wk,
    const float* __restrict__ W1,
    float* __restrict__ Wq1, float* __restrict__ Wk1)
{
    const int id = blockIdx.x * 256 + threadIdx.x;   // 0..32767
    const int which = id >> 14;                      // 0 = Wq, 1 = Wk
    const int rem = id & 16383;
    const int d = rem >> 7;
    const int f = rem & 127;
    const int g = f >> 6, c = f & 63;
    const float* W = which ? Wk : Wq;
    float acc = 0.f;
    #pragma unroll 8
    for (int e = 0; e < DGQ; ++e)
        acc = fmaf(W[d * DQ + g * DGQ + e], W1[e * DGQ + c], acc);
    (which ? Wk1 : Wq1)[d * DQ + f] = acc;
}

// ---------------------------------------------------------------------------
// Kernel 1: projections. One row per block, 256 threads = 128 features x
// 2 K-halves (split-K for occupancy: 1024 blocks x 4 waves = 16 waves/CU).
//   QW1 = x @ Wq1 + b1rep,  KW1 = x @ Wk1,  Vp = permute(x @ Wv)
// Vp[row][g][dg] with feature f = dg*NG+g -> position g*64+dg, so the attn
// A@V pass reads 256B contiguous per wave.
// ---------------------------------------------------------------------------
__global__ __launch_bounds__(256) void proj_kernel(
    const float* __restrict__ x,
    const float* __restrict__ Wq1, const float* __restrict__ Wk1,
    const float* __restrict__ Wv, const float* __restrict__ b1,
    float* __restrict__ QW1, float* __restrict__ KW1, float* __restrict__ Vp)
{
    const int t = threadIdx.x;
    const int f = t & 127, h = t >> 7;
    const int row = blockIdx.x;              // flat b*S+s
    __shared__ float xs[DQ];
    __shared__ float part[3][2][DQ];

    if (t < DQ) xs[t] = x[(size_t)row * DQ + t];
    __syncthreads();

    float aq = 0.f, ak = 0.f, av = 0.f;
    const int d0 = h * 64;
    #pragma unroll 8
    for (int d = 0; d < 64; ++d) {
        const float xv = xs[d0 + d];         // wave-uniform broadcast
        aq = fmaf(xv, Wq1[(size_t)(d0 + d) * DQ + f], aq);
        ak = fmaf(xv, Wk1[(size_t)(d0 + d) * DQ + f], ak);
        av = fmaf(xv, Wv [(size_t)(d0 + d) * DQ + f], av);
    }
    part[0][h][f] = aq; part[1][h][f] = ak; part[2][h][f] = av;
    __syncthreads();

    if (h == 0) {
        QW1[(size_t)row * DQ + f] = aq + part[0][1][f] + b1[f & 63];
        KW1[(size_t)row * DQ + f] = ak + part[1][1][f];
    } else {
        const float v = part[2][0][f] + av;
        Vp[((size_t)row * NGQ + (f & 1)) * DGQ + (f >> 1)] = v;
    }
}

// ---------------------------------------------------------------------------
// Kernel 2: one block per (b, g, i) softmax row; 512 threads, thread t = key j.
// Logit lives in a register through softmax (no LDS round trip).
// 2048 blocks x 512 thr = 4 blocks/CU = 100% occupancy potential (VGPR ~44).
// ---------------------------------------------------------------------------
__global__ __launch_bounds__(512) void attn_kernel(
    const float* __restrict__ QW1, const float* __restrict__ KW1,
    const float* __restrict__ Vp,
    const float* __restrict__ W2, const float* __restrict__ b2,
    const float* __restrict__ W3, const float* __restrict__ b3,
    const float* __restrict__ pos_add, const float* __restrict__ pos_mul,
    float* __restrict__ out)
{
    const int t = threadIdx.x;               // == key index j
    const int i = blockIdx.x & (SQ - 1);
    const int g = (blockIdx.x >> 9) & 1;
    const int b = blockIdx.x >> 10;

    __shared__ float qs[DGQ];
    __shared__ float scores[SQ];
    __shared__ float red[8];
    __shared__ float av[8][DGQ];

    if (t < DGQ) qs[t] = QW1[((size_t)(b * SQ + i)) * DQ + g * DGQ + t];
    // prefetch positional bias early (L3/HBM latency hidden behind MLP)
    const size_t biasoff = ((size_t)g * SQ + i) * SQ + t;
    const float pmv = pos_mul[biasoff];
    const float pav = pos_add[biasoff];
    __syncthreads();

    const float4* krow = reinterpret_cast<const float4*>(
        KW1 + ((size_t)(b * SQ + t)) * DQ + g * DGQ);

    float acc[16];
    #pragma unroll
    for (int o = 0; o < 16; ++o) acc[o] = b2[o];   // uniform -> scalar loads

    #pragma unroll 2
    for (int c4 = 0; c4 < 16; ++c4) {
        const float4 kv = krow[c4];
        const float q0 = qs[c4 * 4 + 0], q1 = qs[c4 * 4 + 1];
        const float q2 = qs[c4 * 4 + 2], q3 = qs[c4 * 4 + 3];
        const float h0 = fmaxf(q0 - kv.x, 0.f);
        const float h1 = fmaxf(q1 - kv.y, 0.f);
        const float h2 = fmaxf(q2 - kv.z, 0.f);
        const float h3 = fmaxf(q3 - kv.w, 0.f);
        const float* w2r = W2 + c4 * 64;           // uniform -> scalar loads
        #pragma unroll
        for (int o = 0; o < 16; ++o) {
            acc[o] = fmaf(h0, w2r[o],      acc[o]);
            acc[o] = fmaf(h1, w2r[16 + o], acc[o]);
            acc[o] = fmaf(h2, w2r[32 + o], acc[o]);
            acc[o] = fmaf(h3, w2r[48 + o], acc[o]);
        }
    }
    float a = b3[0];
    #pragma unroll
    for (int o = 0; o < 16; ++o) a = fmaf(fmaxf(acc[o], 0.f), W3[o], a);
    a = fmaxf(a, 0.f);
    const float logit = fmaf(a, pmv, pav);

    // ---- softmax (logit stays in-register) ----
    float m = logit;
    #pragma unroll
    for (int off = 32; off > 0; off >>= 1) m = fmaxf(m, __shfl_xor(m, off));
    const int wave = t >> 6;
    if ((t & 63) == 0) red[wave] = m;
    __syncthreads();
    m = fmaxf(fmaxf(fmaxf(red[0], red[1]), fmaxf(red[2], red[3])),
              fmaxf(fmaxf(red[4], red[5]), fmaxf(red[6], red[7])));
    const float e = __expf(logit - m);
    scores[t] = e;
    float s = e;
    #pragma unroll
    for (int off = 32; off > 0; off >>= 1) s += __shfl_xor(s, off);
    __syncthreads();                      // all reads of red(max) done; scores visible
    if ((t & 63) == 0) red[wave] = s;
    __syncthreads();
    const float inv = 1.f / (red[0] + red[1] + red[2] + red[3] +
                             red[4] + red[5] + red[6] + red[7]);

    // ---- A @ V: 8 waves split the 512 keys; Vp gives 256B coalesced rows ----
    const int dim = t & 63, q = t >> 6;
    const float* vbase = Vp + (((size_t)(b * SQ + q * 64)) * NGQ + g) * DGQ + dim;
    float accv = 0.f;
    #pragma unroll 4
    for (int k = 0; k < 64; ++k)
        accv = fmaf(scores[q * 64 + k], vbase[(size_t)k * (NGQ * DGQ)], accv);
    av[q][dim] = accv;
    __syncthreads();
    if (t < DGQ) {
        float sum = 0.f;
        #pragma unroll
        for (int q2 = 0; q2 < 8; ++q2) sum += av[q2][t];
        out[((size_t)(b * SQ + i)) * DQ + t * NGQ + g] = sum * inv;
    }
}

extern "C" void kernel_launch(void* const* d_in, const int* in_sizes, int n_in,
                              void* d_out, int out_size, void* d_ws, size_t ws_size,
                              hipStream_t stream) {
    const float* x       = (const float*)d_in[0];
    const float* pos_add = (const float*)d_in[1];
    const float* pos_mul = (const float*)d_in[2];
    const float* Wq      = (const float*)d_in[3];
    const float* Wk      = (const float*)d_in[4];
    const float* Wv      = (const float*)d_in[5];
    const float* W1      = (const float*)d_in[6];
    const float* b1      = (const float*)d_in[7];
    const float* W2      = (const float*)d_in[8];
    const float* b2      = (const float*)d_in[9];
    const float* W3      = (const float*)d_in[10];
    const float* b3      = (const float*)d_in[11];
    float* out = (float*)d_out;

    float* ws  = (float*)d_ws;
    float* Wq1 = ws;
    float* Wk1 = ws + 16384;
    float* QW1 = ws + 32768;
    float* KW1 = ws + 163840;
    float* Vp  = ws + 294912;

    fuse_w_kernel<<<128, 256, 0, stream>>>(Wq, Wk, W1, Wq1, Wk1);
    proj_kernel<<<BQ * SQ, 256, 0, stream>>>(x, Wq1, Wk1, Wv, b1, QW1, KW1, Vp);
    attn_kernel<<<BQ * NGQ * SQ, 512, 0, stream>>>(QW1, KW1, Vp, W2, b2, W3, b3,
                                                   pos_add, pos_mul, out);
}

// Round 3
// 129.580 us; speedup vs baseline: 1.1935x; 1.0636x over previous
//
#include <hip/hip_runtime.h>

// Problem constants (B=2, S=512, D=128, DG=64, NG=2)
#define BQ 2
#define SQ 512
#define DQ 128
#define DGQ 64
#define NGQ 2

typedef float float2v __attribute__((ext_vector_type(2)));

// ws layout (floats):
//   QW1 : [B*S][128]          @ 0        (= (x@Wq)@blkdiag(W1) + b1, per group)
//   KW1 : [B*S][128]          @ 131072
//   Vp  : [B*S][NG][DG]       @ 262144   (group-major V for coalesced A@V)

// ---------------------------------------------------------------------------
// Kernel 1: fused projections. One block per row (1024 blocks x 256 thr).
// Phase A: Q,K,V rows via split-K over 2 halves (part[] in LDS).
// Phase B: apply W1 per group: QW1 = Q@blkdiag(W1)+b1, KW1 = K@blkdiag(W1).
// Exploits linearity: relu((Q_i-K_j)@W1 + b1) == relu(QW1_i - KW1_j).
// ---------------------------------------------------------------------------
__global__ __launch_bounds__(256) void proj_kernel(
    const float* __restrict__ x,
    const float* __restrict__ Wq, const float* __restrict__ Wk,
    const float* __restrict__ Wv,
    const float* __restrict__ W1, const float* __restrict__ b1,
    float* __restrict__ QW1, float* __restrict__ KW1, float* __restrict__ Vp)
{
    const int t = threadIdx.x;
    const int row = blockIdx.x;            // flat b*S+s, 1024 rows
    __shared__ float xs[DQ];
    __shared__ float part[3][2][DQ];
    __shared__ float qs[DQ], ks[DQ];

    if (t < DQ) xs[t] = x[(size_t)row * DQ + t];
    __syncthreads();

    const int f = t & 127, h = t >> 7;     // feature, K-half
    float aq = 0.f, ak = 0.f, av = 0.f;
    const int d0 = h * 64;
    #pragma unroll 8
    for (int d = 0; d < 64; ++d) {
        const float xv = xs[d0 + d];                       // LDS broadcast
        const size_t o = (size_t)(d0 + d) * DQ + f;        // 256B/wave coalesced
        aq = fmaf(xv, Wq[o], aq);
        ak = fmaf(xv, Wk[o], ak);
        av = fmaf(xv, Wv[o], av);
    }
    part[0][h][f] = aq; part[1][h][f] = ak; part[2][h][f] = av;
    __syncthreads();

    if (t < DQ) {
        qs[t] = part[0][0][t] + part[0][1][t];
        const float v = part[2][0][t] + part[2][1][t];
        // feature f = dg*NG+g  ->  Vp[row][g][dg]
        Vp[((size_t)row * NGQ + (t & 1)) * DGQ + (t >> 1)] = v;
    } else {
        const int f2 = t - DQ;
        ks[f2] = part[1][0][f2] + part[1][1][f2];
    }
    __syncthreads();

    // Phase B: 256 tasks = {q-side, k-side} x 128 features
    const int fb = t & 127, side = t >> 7;
    const int g = fb >> 6, c = fb & 63;
    const float* src = side ? ks : qs;
    float acc = side ? 0.f : b1[c];
    #pragma unroll 8
    for (int e = 0; e < 64; ++e)
        acc = fmaf(src[g * 64 + e], W1[e * DGQ + c], acc);
    (side ? KW1 : QW1)[(size_t)row * DQ + fb] = acc;
}

// ---------------------------------------------------------------------------
// Kernel 2: one block per (b, g, i-pair); 512 threads, thread t = key j.
// TWO queries per block: krow/V loads amortized over 2 logit rows, and the
// W2 stage runs as v_pk_fma_f32 (float2 accumulators) for 2x fp32 rate.
// Grid 1024 = exactly 4 blocks/CU, one full round, no tail.
// ---------------------------------------------------------------------------
__global__ __launch_bounds__(512) void attn_kernel(
    const float* __restrict__ QW1, const float* __restrict__ KW1,
    const float* __restrict__ Vp,
    const float* __restrict__ W2, const float* __restrict__ b2,
    const float* __restrict__ W3, const float* __restrict__ b3,
    const float* __restrict__ pos_add, const float* __restrict__ pos_mul,
    float* __restrict__ out)
{
    const int t = threadIdx.x;                  // key index j
    const int ipair = blockIdx.x & 255;
    const int g = (blockIdx.x >> 8) & 1;
    const int b = blockIdx.x >> 9;
    const int i0 = ipair * 2;

    __shared__ __align__(16) float qsl[2][DGQ];
    __shared__ __align__(8)  float sc[SQ * 2];     // interleaved {e0,e1} per key
    __shared__ float redm[2][8], reds[2][8];
    __shared__ float avs[2][8][DGQ];

    if (t < 2 * DGQ) {
        const int qq = t >> 6, e = t & 63;
        qsl[qq][e] = QW1[((size_t)(b * SQ + i0 + qq)) * DQ + g * DGQ + e];
    }
    // positional bias prefetch (no batch dim: shape [1,NG,1,S,S])
    const size_t bo0 = ((size_t)g * SQ + i0) * SQ + t;
    const float pm0 = pos_mul[bo0],      pa0 = pos_add[bo0];
    const float pm1 = pos_mul[bo0 + SQ], pa1 = pos_add[bo0 + SQ];
    __syncthreads();

    const float4* krow = reinterpret_cast<const float4*>(
        KW1 + ((size_t)(b * SQ + t)) * DQ + g * DGQ);
    const float2v* qv0 = reinterpret_cast<const float2v*>(&qsl[0][0]);
    const float2v* qv1 = reinterpret_cast<const float2v*>(&qsl[1][0]);
    const float2v* b2v = reinterpret_cast<const float2v*>(b2);

    float2v acc0[8], acc1[8];
    #pragma unroll
    for (int o = 0; o < 8; ++o) { acc0[o] = b2v[o]; acc1[o] = b2v[o]; }

    #pragma unroll 2
    for (int c4 = 0; c4 < 16; ++c4) {
        const float4 kv = krow[c4];
        const float2v k01 = {kv.x, kv.y}, k23 = {kv.z, kv.w};
        const float2v d01a = qv0[c4 * 2] - k01,     d23a = qv0[c4 * 2 + 1] - k23;
        const float2v d01b = qv1[c4 * 2] - k01,     d23b = qv1[c4 * 2 + 1] - k23;
        const float ha0 = fmaxf(d01a.x, 0.f), ha1 = fmaxf(d01a.y, 0.f);
        const float ha2 = fmaxf(d23a.x, 0.f), ha3 = fmaxf(d23a.y, 0.f);
        const float hb0 = fmaxf(d01b.x, 0.f), hb1 = fmaxf(d01b.y, 0.f);
        const float hb2 = fmaxf(d23b.x, 0.f), hb3 = fmaxf(d23b.y, 0.f);
        const float2v* w2r = reinterpret_cast<const float2v*>(W2 + c4 * 64);
        #pragma unroll
        for (int o = 0; o < 8; ++o) {
            const float2v w0 = w2r[o], w1 = w2r[8 + o];
            const float2v w2_ = w2r[16 + o], w3_ = w2r[24 + o];
            acc0[o] += ha0 * w0;  acc0[o] += ha1 * w1;
            acc0[o] += ha2 * w2_; acc0[o] += ha3 * w3_;
            acc1[o] += hb0 * w0;  acc1[o] += hb1 * w1;
            acc1[o] += hb2 * w2_; acc1[o] += hb3 * w3_;
        }
    }
    float a0 = b3[0], a1 = b3[0];
    #pragma unroll
    for (int o = 0; o < 8; ++o) {
        a0 = fmaf(fmaxf(acc0[o].x, 0.f), W3[2 * o], a0);
        a0 = fmaf(fmaxf(acc0[o].y, 0.f), W3[2 * o + 1], a0);
        a1 = fmaf(fmaxf(acc1[o].x, 0.f), W3[2 * o], a1);
        a1 = fmaf(fmaxf(acc1[o].y, 0.f), W3[2 * o + 1], a1);
    }
    const float logit0 = fmaf(fmaxf(a0, 0.f), pm0, pa0);
    const float logit1 = fmaf(fmaxf(a1, 0.f), pm1, pa1);

    // ---- softmax for both queries (logits stay in-register) ----
    float m0 = logit0, m1 = logit1;
    #pragma unroll
    for (int off = 32; off > 0; off >>= 1) {
        m0 = fmaxf(m0, __shfl_xor(m0, off));
        m1 = fmaxf(m1, __shfl_xor(m1, off));
    }
    const int wave = t >> 6;
    if ((t & 63) == 0) { redm[0][wave] = m0; redm[1][wave] = m1; }
    __syncthreads();
    float M0 = redm[0][0], M1 = redm[1][0];
    #pragma unroll
    for (int w = 1; w < 8; ++w) {
        M0 = fmaxf(M0, redm[0][w]); M1 = fmaxf(M1, redm[1][w]);
    }
    const float e0 = __expf(logit0 - M0);
    const float e1 = __expf(logit1 - M1);
    *reinterpret_cast<float2v*>(&sc[t * 2]) = float2v{e0, e1};
    float s0 = e0, s1 = e1;
    #pragma unroll
    for (int off = 32; off > 0; off >>= 1) {
        s0 += __shfl_xor(s0, off);
        s1 += __shfl_xor(s1, off);
    }
    if ((t & 63) == 0) { reds[0][wave] = s0; reds[1][wave] = s1; }
    __syncthreads();
    float S0 = 0.f, S1 = 0.f;
    #pragma unroll
    for (int w = 0; w < 8; ++w) { S0 += reds[0][w]; S1 += reds[1][w]; }
    const float inv0 = 1.f / S0, inv1 = 1.f / S1;

    // ---- A@V: 8 waves split the 512 keys; V load shared across 2 queries ----
    const int dim = t & 63, q = t >> 6;
    const float* vbase = Vp + (((size_t)(b * SQ + q * 64)) * NGQ + g) * DGQ + dim;
    float2v accv = {0.f, 0.f};
    #pragma unroll 8
    for (int k = 0; k < 64; ++k) {
        const float v = vbase[(size_t)k * (NGQ * DGQ)];
        const float2v sv = *reinterpret_cast<const float2v*>(&sc[(q * 64 + k) * 2]);
        accv += v * sv;                      // v_pk_fma
    }
    avs[0][q][dim] = accv.x;
    avs[1][q][dim] = accv.y;
    __syncthreads();
    if (t < 2 * DGQ) {
        const int qq = t >> 6, d = t & 63;
        float sum = 0.f;
        #pragma unroll
        for (int w = 0; w < 8; ++w) sum += avs[qq][w][d];
        out[((size_t)(b * SQ + i0 + qq)) * DQ + d * NGQ + g] =
            sum * (qq ? inv1 : inv0);
    }
}

extern "C" void kernel_launch(void* const* d_in, const int* in_sizes, int n_in,
                              void* d_out, int out_size, void* d_ws, size_t ws_size,
                              hipStream_t stream) {
    const float* x       = (const float*)d_in[0];
    const float* pos_add = (const float*)d_in[1];
    const float* pos_mul = (const float*)d_in[2];
    const float* Wq      = (const float*)d_in[3];
    const float* Wk      = (const float*)d_in[4];
    const float* Wv      = (const float*)d_in[5];
    const float* W1      = (const float*)d_in[6];
    const float* b1      = (const float*)d_in[7];
    const float* W2      = (const float*)d_in[8];
    const float* b2      = (const float*)d_in[9];
    const float* W3      = (const float*)d_in[10];
    const float* b3      = (const float*)d_in[11];
    float* out = (float*)d_out;

    float* ws  = (float*)d_ws;
    float* QW1 = ws;
    float* KW1 = ws + 131072;
    float* Vp  = ws + 262144;

    proj_kernel<<<BQ * SQ, 256, 0, stream>>>(x, Wq, Wk, Wv, W1, b1,
                                             QW1, KW1, Vp);
    attn_kernel<<<BQ * NGQ * SQ / 2, 512, 0, stream>>>(QW1, KW1, Vp, W2, b2,
                                                       W3, b3, pos_add, pos_mul,
                                                       out);
}

// Round 4
// 119.049 us; speedup vs baseline: 1.2991x; 1.0885x over previous
//
#include <hip/hip_runtime.h>

// Problem constants (B=2, S=512, D=128, DG=64, NG=2)
#define BQ 2
#define SQ 512
#define DQ 128
#define DGQ 64
#define NGQ 2

typedef float float2v __attribute__((ext_vector_type(2)));

// ws layout (floats):
//   QW1 : [B*S][128]          @ 0        (= (x@Wq)@blkdiag(W1) + b1, per group)
//   KW1 : [B*S][128]          @ 131072
//   Vp  : [B*S][NG][DG]       @ 262144   (group-major V for coalesced A@V)

// ---------------------------------------------------------------------------
// Kernel 1: fused projections. One block per row (1024 blocks x 256 thr).
// Phase A: Q,K,V rows via split-K over 2 halves (part[] in LDS).
// Phase B: apply W1 per group: QW1 = Q@blkdiag(W1)+b1, KW1 = K@blkdiag(W1).
// Exploits linearity: relu((Q_i-K_j)@W1 + b1) == relu(QW1_i - KW1_j).
// ---------------------------------------------------------------------------
__global__ __launch_bounds__(256) void proj_kernel(
    const float* __restrict__ x,
    const float* __restrict__ Wq, const float* __restrict__ Wk,
    const float* __restrict__ Wv,
    const float* __restrict__ W1, const float* __restrict__ b1,
    float* __restrict__ QW1, float* __restrict__ KW1, float* __restrict__ Vp)
{
    const int t = threadIdx.x;
    const int row = blockIdx.x;            // flat b*S+s, 1024 rows
    __shared__ float xs[DQ];
    __shared__ float part[3][2][DQ];
    __shared__ float qs[DQ], ks[DQ];

    if (t < DQ) xs[t] = x[(size_t)row * DQ + t];
    __syncthreads();

    const int f = t & 127, h = t >> 7;     // feature, K-half
    float aq = 0.f, ak = 0.f, av = 0.f;
    const int d0 = h * 64;
    #pragma unroll 8
    for (int d = 0; d < 64; ++d) {
        const float xv = xs[d0 + d];                       // LDS broadcast
        const size_t o = (size_t)(d0 + d) * DQ + f;        // 256B/wave coalesced
        aq = fmaf(xv, Wq[o], aq);
        ak = fmaf(xv, Wk[o], ak);
        av = fmaf(xv, Wv[o], av);
    }
    part[0][h][f] = aq; part[1][h][f] = ak; part[2][h][f] = av;
    __syncthreads();

    if (t < DQ) {
        qs[t] = part[0][0][t] + part[0][1][t];
        const float v = part[2][0][t] + part[2][1][t];
        // feature f = dg*NG+g  ->  Vp[row][g][dg]
        Vp[((size_t)row * NGQ + (t & 1)) * DGQ + (t >> 1)] = v;
    } else {
        const int f2 = t - DQ;
        ks[f2] = part[1][0][f2] + part[1][1][f2];
    }
    __syncthreads();

    // Phase B: 256 tasks = {q-side, k-side} x 128 features
    const int fb = t & 127, side = t >> 7;
    const int g = fb >> 6, c = fb & 63;
    const float* src = side ? ks : qs;
    float acc = side ? 0.f : b1[c];
    #pragma unroll 8
    for (int e = 0; e < 64; ++e)
        acc = fmaf(src[g * 64 + e], W1[e * DGQ + c], acc);
    (side ? KW1 : QW1)[(size_t)row * DQ + fb] = acc;
}

// ---------------------------------------------------------------------------
// Kernel 2: one block per (b, g, i-pair); 512 threads, thread t = key j.
// Two queries per block; W2 stage in v_pk_fma_f32; krow double-buffered in
// registers (2x float4 in flight while 2x compute) to cover L2 latency.
// VGPR budget note: at 512-thr blocks, anything <=64 VGPR gives the same
// 4 blocks/CU -- the prefetch registers are free occupancy-wise.
// ---------------------------------------------------------------------------
__global__ __launch_bounds__(512) void attn_kernel(
    const float* __restrict__ QW1, const float* __restrict__ KW1,
    const float* __restrict__ Vp,
    const float* __restrict__ W2, const float* __restrict__ b2,
    const float* __restrict__ W3, const float* __restrict__ b3,
    const float* __restrict__ pos_add, const float* __restrict__ pos_mul,
    float* __restrict__ out)
{
    const int t = threadIdx.x;                  // key index j
    const int ipair = blockIdx.x & 255;
    const int g = (blockIdx.x >> 8) & 1;
    const int b = blockIdx.x >> 9;
    const int i0 = ipair * 2;

    __shared__ __align__(16) float qsl[2][DGQ];
    __shared__ __align__(8)  float sc[SQ * 2];     // interleaved {e0,e1} per key
    __shared__ float redm[2][8], reds[2][8];
    __shared__ float avs[2][8][DGQ];

    if (t < 2 * DGQ) {
        const int qq = t >> 6, e = t & 63;
        qsl[qq][e] = QW1[((size_t)(b * SQ + i0 + qq)) * DQ + g * DGQ + e];
    }
    // positional bias prefetch (no batch dim: shape [1,NG,1,S,S])
    const size_t bo0 = ((size_t)g * SQ + i0) * SQ + t;
    const float pm0 = pos_mul[bo0],      pa0 = pos_add[bo0];
    const float pm1 = pos_mul[bo0 + SQ], pa1 = pos_add[bo0 + SQ];
    __syncthreads();

    const float4* krow = reinterpret_cast<const float4*>(
        KW1 + ((size_t)(b * SQ + t)) * DQ + g * DGQ);
    const float4* qv0 = reinterpret_cast<const float4*>(&qsl[0][0]);
    const float4* qv1 = reinterpret_cast<const float4*>(&qsl[1][0]);
    const float2v* b2v = reinterpret_cast<const float2v*>(b2);
    const float2v zero2 = {0.f, 0.f};

    float2v acc0[8], acc1[8];
    #pragma unroll
    for (int o = 0; o < 8; ++o) { acc0[o] = b2v[o]; acc1[o] = b2v[o]; }

    float4 kva = krow[0], kvb = krow[1];
    #pragma unroll
    for (int grp = 0; grp < 8; ++grp) {
        float4 nka, nkb;
        if (grp < 7) { nka = krow[grp * 2 + 2]; nkb = krow[grp * 2 + 3]; }
        #pragma unroll
        for (int u = 0; u < 2; ++u) {
            const int c4 = grp * 2 + u;
            const float4 kv = u ? kvb : kva;
            const float4 qa = qv0[c4], qb = qv1[c4];       // ds_read_b128
            const float2v k01 = {kv.x, kv.y}, k23 = {kv.z, kv.w};
            const float2v ha01 = __builtin_elementwise_max(
                float2v{qa.x, qa.y} - k01, zero2);         // v_pk_max
            const float2v ha23 = __builtin_elementwise_max(
                float2v{qa.z, qa.w} - k23, zero2);
            const float2v hb01 = __builtin_elementwise_max(
                float2v{qb.x, qb.y} - k01, zero2);
            const float2v hb23 = __builtin_elementwise_max(
                float2v{qb.z, qb.w} - k23, zero2);
            const float2v* w2r = reinterpret_cast<const float2v*>(W2 + c4 * 64);
            #pragma unroll
            for (int o = 0; o < 8; ++o) {
                const float2v w0 = w2r[o],      w1 = w2r[8 + o];
                const float2v w2_ = w2r[16 + o], w3_ = w2r[24 + o];
                acc0[o] += ha01.x * w0;  acc0[o] += ha01.y * w1;
                acc0[o] += ha23.x * w2_; acc0[o] += ha23.y * w3_;
                acc1[o] += hb01.x * w0;  acc1[o] += hb01.y * w1;
                acc1[o] += hb23.x * w2_; acc1[o] += hb23.y * w3_;
            }
        }
        kva = nka; kvb = nkb;
    }
    float a0 = b3[0], a1 = b3[0];
    #pragma unroll
    for (int o = 0; o < 8; ++o) {
        a0 = fmaf(fmaxf(acc0[o].x, 0.f), W3[2 * o], a0);
        a0 = fmaf(fmaxf(acc0[o].y, 0.f), W3[2 * o + 1], a0);
        a1 = fmaf(fmaxf(acc1[o].x, 0.f), W3[2 * o], a1);
        a1 = fmaf(fmaxf(acc1[o].y, 0.f), W3[2 * o + 1], a1);
    }
    const float logit0 = fmaf(fmaxf(a0, 0.f), pm0, pa0);
    const float logit1 = fmaf(fmaxf(a1, 0.f), pm1, pa1);

    // ---- softmax for both queries (logits stay in-register) ----
    float m0 = logit0, m1 = logit1;
    #pragma unroll
    for (int off = 32; off > 0; off >>= 1) {
        m0 = fmaxf(m0, __shfl_xor(m0, off));
        m1 = fmaxf(m1, __shfl_xor(m1, off));
    }
    const int wave = t >> 6;
    if ((t & 63) == 0) { redm[0][wave] = m0; redm[1][wave] = m1; }
    __syncthreads();
    float M0 = redm[0][0], M1 = redm[1][0];
    #pragma unroll
    for (int w = 1; w < 8; ++w) {
        M0 = fmaxf(M0, redm[0][w]); M1 = fmaxf(M1, redm[1][w]);
    }
    const float e0 = __expf(logit0 - M0);
    const float e1 = __expf(logit1 - M1);
    *reinterpret_cast<float2v*>(&sc[t * 2]) = float2v{e0, e1};
    float s0 = e0, s1 = e1;
    #pragma unroll
    for (int off = 32; off > 0; off >>= 1) {
        s0 += __shfl_xor(s0, off);
        s1 += __shfl_xor(s1, off);
    }
    if ((t & 63) == 0) { reds[0][wave] = s0; reds[1][wave] = s1; }
    __syncthreads();
    float S0 = 0.f, S1 = 0.f;
    #pragma unroll
    for (int w = 0; w < 8; ++w) { S0 += reds[0][w]; S1 += reds[1][w]; }
    const float inv0 = 1.f / S0, inv1 = 1.f / S1;

    // ---- A@V: 8 waves split the 512 keys; V load shared across 2 queries ----
    const int dim = t & 63, q = t >> 6;
    const float* vbase = Vp + (((size_t)(b * SQ + q * 64)) * NGQ + g) * DGQ + dim;
    float2v accv = {0.f, 0.f};
    #pragma unroll 16
    for (int k = 0; k < 64; ++k) {
        const float v = vbase[(size_t)k * (NGQ * DGQ)];
        const float2v sv = *reinterpret_cast<const float2v*>(&sc[(q * 64 + k) * 2]);
        accv += v * sv;                      // v_pk_fma
    }
    avs[0][q][dim] = accv.x;
    avs[1][q][dim] = accv.y;
    __syncthreads();
    if (t < 2 * DGQ) {
        const int qq = t >> 6, d = t & 63;
        float sum = 0.f;
        #pragma unroll
        for (int w = 0; w < 8; ++w) sum += avs[qq][w][d];
        out[((size_t)(b * SQ + i0 + qq)) * DQ + d * NGQ + g] =
            sum * (qq ? inv1 : inv0);
    }
}

extern "C" void kernel_launch(void* const* d_in, const int* in_sizes, int n_in,
                              void* d_out, int out_size, void* d_ws, size_t ws_size,
                              hipStream_t stream) {
    const float* x       = (const float*)d_in[0];
    const float* pos_add = (const float*)d_in[1];
    const float* pos_mul = (const float*)d_in[2];
    const float* Wq      = (const float*)d_in[3];
    const float* Wk      = (const float*)d_in[4];
    const float* Wv      = (const float*)d_in[5];
    const float* W1      = (const float*)d_in[6];
    const float* b1      = (const float*)d_in[7];
    const float* W2      = (const float*)d_in[8];
    const float* b2      = (const float*)d_in[9];
    const float* W3      = (const float*)d_in[10];
    const float* b3      = (const float*)d_in[11];
    float* out = (float*)d_out;

    float* ws  = (float*)d_ws;
    float* QW1 = ws;
    float* KW1 = ws + 131072;
    float* Vp  = ws + 262144;

    proj_kernel<<<BQ * SQ, 256, 0, stream>>>(x, Wq, Wk, Wv, W1, b1,
                                             QW1, KW1, Vp);
    attn_kernel<<<BQ * NGQ * SQ / 2, 512, 0, stream>>>(QW1, KW1, Vp, W2, b2,
                                                       W3, b3, pos_add, pos_mul,
                                                       out);
}